// Round 9
// baseline (287.528 us; speedup 1.0000x reference)
//
#include <hip/hip_runtime.h>

#define N_ 16384
#define D_ 256
#define LOG2E 1.4426950408889634f
#define HEXP2(x) __builtin_amdgcn_exp2f(x)

typedef __attribute__((ext_vector_type(8))) short short8;
typedef __attribute__((ext_vector_type(16))) float floatx16;

typedef __attribute__((address_space(1))) const unsigned int gu32_t;
typedef __attribute__((address_space(3))) unsigned int lu32_t;

__device__ __forceinline__ void async16(const void* g, void* l) {
  __builtin_amdgcn_global_load_lds((gu32_t*)g, (lu32_t*)l, 16, 0, 0);
}

__device__ __forceinline__ unsigned short f2bf(float x) {
  unsigned int u = __float_as_uint(x);
  u += 0x7fffu + ((u >> 16) & 1u);
  return (unsigned short)(u >> 16);
}

// ---------------- prep: fp32 -> bf16, packed in 32x32x16-fragment order ----------------
// 16B unit uidx = (G*16+ks)*64 + h*32 + m  holds  X[G*32+m][ks*16+h*8 .. +8)
// -> fragment (G, ks) = contiguous 1024B, lane-contiguous (lane = h*32+m).
__global__ void prep_pack(const float* __restrict__ img, const float* __restrict__ txt,
                          const float* __restrict__ ls, short* __restrict__ PA,
                          short* __restrict__ PB, float* __restrict__ accv) {
  int t = blockIdx.x * 256 + threadIdx.x;  // 0 .. N*D/8-1
  int row = t >> 5, kq = t & 31;
  int G = row >> 5, m = row & 31, ks = kq >> 1, h = kq & 1;
  int uidx = (G * 16 + ks) * 64 + h * 32 + m;
  float s2 = ls[0] * LOG2E;
  const float4* sa = (const float4*)(img + (size_t)row * D_ + kq * 8);
  const float4* sb = (const float4*)(txt + (size_t)row * D_ + kq * 8);
  float4 a0 = sa[0], a1 = sa[1];
  float4 b0 = sb[0], b1 = sb[1];
  short8 oa, ob;
  oa[0] = (short)f2bf(a0.x * s2); oa[1] = (short)f2bf(a0.y * s2);
  oa[2] = (short)f2bf(a0.z * s2); oa[3] = (short)f2bf(a0.w * s2);
  oa[4] = (short)f2bf(a1.x * s2); oa[5] = (short)f2bf(a1.y * s2);
  oa[6] = (short)f2bf(a1.z * s2); oa[7] = (short)f2bf(a1.w * s2);
  ob[0] = (short)f2bf(b0.x); ob[1] = (short)f2bf(b0.y);
  ob[2] = (short)f2bf(b0.z); ob[3] = (short)f2bf(b0.w);
  ob[4] = (short)f2bf(b1.x); ob[5] = (short)f2bf(b1.y);
  ob[6] = (short)f2bf(b1.z); ob[7] = (short)f2bf(b1.w);
  ((short8*)PA)[uidx] = oa;
  ((short8*)PB)[uidx] = ob;
  if (t == 0) accv[0] = 0.0f;
}

// ---------------- diag: exact fp32 diagonal in log2 domain ----------------
__global__ void diag_kernel(const float* __restrict__ img, const float* __restrict__ txt,
                            const float* __restrict__ ls, float* __restrict__ diag2) {
  int row = blockIdx.x * 4 + (threadIdx.x >> 6);
  int lane = threadIdx.x & 63;
  float4 a = ((const float4*)(img + (size_t)row * D_))[lane];
  float4 b = ((const float4*)(txt + (size_t)row * D_))[lane];
  float s = a.x * b.x + a.y * b.y + a.z * b.z + a.w * b.w;
  #pragma unroll
  for (int off = 1; off < 64; off <<= 1) s += __shfl_xor(s, off);
  if (lane == 0) diag2[row] = s * ls[0] * LOG2E;
}

// ---------------- gemm + stats: A-in-registers, depth-1 issue-ahead B pipeline ----------------
// Grid (128 stripes [x, fast], 8 colgroups [y]). 256 thr = 4 waves (2 wr x 2 wc).
// Wave tile 64x64 = 2x2 of mfma_32x32x16; A panel (64 rows x K=256) in 128 VGPRs.
// B streamed via global_load_lds into 2x16KB LDS. SAFETY: LDS-DMA completion order vs
// partial vmcnt is not guaranteed -> full vmcnt(0) drain before each compute; chunk g+1
// issued right after, overlapping compute(g) + stats (bare barriers keep it in flight).
__global__ __launch_bounds__(256, 2)
void gemm_stats(const short* __restrict__ PA, const short* __restrict__ PB,
                float2* __restrict__ pR, float2* __restrict__ pC) {
  __shared__ __align__(16) char smem[73744];
  // [0,32768): B staging dbuf (2 x 16KB, 16 frags x 1KB each)
  // [32768,71680): rowbuf f32 [wr*64+slot][76] (38912 B)
  // [71680,73728): colbuf float2[2][128]; [73728,73744): wmaxb f32[4]
  float* rowbuf  = (float*)(smem + 32768);
  float2* colbuf = (float2*)(smem + 71680);
  float* wmaxb   = (float*)(smem + 73728);

  const int tid = threadIdx.x, lane = tid & 63, wv = tid >> 6;
  const int wr = wv >> 1, wc = wv & 1;
  const int m = lane & 31, h = lane >> 5;
  const int stripe = blockIdx.x, by = blockIdx.y;

  // ---- A panel into registers: rows stripe*128 + wr*64 .. +64, all K
  short8 areg[2][16];
  #pragma unroll
  for (int g = 0; g < 2; ++g)
    #pragma unroll
    for (int ks = 0; ks < 16; ++ks)
      areg[g][ks] = *(const short8*)(PA +
          ((size_t)((stripe * 4 + wr * 2 + g) * 16 + ks)) * 512 + lane * 8);
  asm volatile("s_waitcnt vmcnt(0)" ::: "memory");

  floatx16 acc[2][2];

  // stage chunk (jj2, c2) -> buffer bufsel. Wave wv stages ks-slice wv for 4 ct frags.
  auto issue = [&](int jj2, int c2, int bufsel) {
    const short* base = PB + ((size_t)((by * 64 + jj2 * 4) * 16) + c2 * 4 + wv) * 512 + lane * 8;
    char* dst = smem + bufsel * 16384 + wv * 1024;
    #pragma unroll
    for (int ct = 0; ct < 4; ++ct)
      async16(base + (size_t)ct * 8192, dst + ct * 4096);
  };
  auto compute = [&](int c, int bufsel) {
    char* base = smem + bufsel * 16384 + lane * 16;
    #pragma unroll
    for (int ksl = 0; ksl < 4; ++ksl) {
      short8 b0 = *(const short8*)(base + ((wc * 2 + 0) * 4 + ksl) * 1024);
      short8 b1 = *(const short8*)(base + ((wc * 2 + 1) * 4 + ksl) * 1024);
      int ks = c * 4 + ksl;  // compile-time under unroll
      acc[0][0] = __builtin_amdgcn_mfma_f32_32x32x16_bf16(areg[0][ks], b0, acc[0][0], 0, 0, 0);
      acc[1][0] = __builtin_amdgcn_mfma_f32_32x32x16_bf16(areg[1][ks], b0, acc[1][0], 0, 0, 0);
      acc[0][1] = __builtin_amdgcn_mfma_f32_32x32x16_bf16(areg[0][ks], b1, acc[0][1], 0, 0, 0);
      acc[1][1] = __builtin_amdgcn_mfma_f32_32x32x16_bf16(areg[1][ks], b1, acc[1][1], 0, 0, 0);
    }
  };

  issue(0, 0, 0);  // prologue: chunk 0 -> buf 0

  float Mr = -3.0e38f, Sr = 0.f;  // row LSE state: row = stripe*128 + wr*64 + wc*32 + m

  for (int jj = 0; jj < 16; ++jj) {
    #pragma unroll
    for (int rt = 0; rt < 2; ++rt)
      #pragma unroll
      for (int ctl = 0; ctl < 2; ++ctl)
        #pragma unroll
        for (int r = 0; r < 16; ++r) acc[rt][ctl][r] = 0.f;

    #pragma unroll
    for (int c = 0; c < 4; ++c) {
      // chunk g = jj*4+c is in flight (issued last iteration / prologue) into buf g&1
      asm volatile("s_waitcnt vmcnt(0)" ::: "memory");   // LDS-DMA: only vmcnt(0) is safe
      __builtin_amdgcn_s_barrier();
      asm volatile("" ::: "memory");
      int g1 = jj * 4 + c + 1;
      if (g1 < 64) issue(g1 >> 2, g1 & 3, g1 & 1);        // overlap compute(g) [+ stats]
      compute(c, c & 1);
      asm volatile("" ::: "memory");
      __builtin_amdgcn_s_barrier();                       // bare: g1 DMA stays in flight
      asm volatile("" ::: "memory");
    }

    // ---- stats. acc[rt][ctl][reg]: row(in tile) = wr*64+rt*32+(reg&3)+8*(reg>>2)+4*h
    //                                col(in tile) = wc*64+ctl*32+m
    float v = -3.0e38f;
    #pragma unroll
    for (int rt = 0; rt < 2; ++rt)
      #pragma unroll
      for (int ctl = 0; ctl < 2; ++ctl)
        #pragma unroll
        for (int r = 0; r < 16; ++r) v = fmaxf(v, acc[rt][ctl][r]);
    #pragma unroll
    for (int off = 1; off < 64; off <<= 1) v = fmaxf(v, __shfl_xor(v, off));
    float msub = v - 96.f;
    if (lane == 0) wmaxb[wv] = msub;  // per-wave msub exchange (read in phase 5)

    #pragma unroll
    for (int rt = 0; rt < 2; ++rt)
      #pragma unroll
      for (int ctl = 0; ctl < 2; ++ctl)
        #pragma unroll
        for (int r = 0; r < 16; ++r) acc[rt][ctl][r] = HEXP2(acc[rt][ctl][r] - msub);

    // col partials: sum over 64 rows of wave tile (reg-local + xor32)
    #pragma unroll
    for (int ctl = 0; ctl < 2; ++ctl) {
      float cp = 0.f;
      #pragma unroll
      for (int r = 0; r < 16; ++r) cp += acc[0][ctl][r] + acc[1][ctl][r];
      cp += __shfl_xor(cp, 32);
      if (h == 0) colbuf[wr * 128 + wc * 64 + ctl * 32 + m] = make_float2(msub, cp);
    }

    // row partials: ctl-add, pack 4 rows -> float4, rowbuf[(wr*64+slot)*76 + row]
    #pragma unroll
    for (int rt = 0; rt < 2; ++rt)
      #pragma unroll
      for (int rq = 0; rq < 4; ++rq) {
        float4 rp;
        rp.x = acc[rt][0][rq * 4 + 0] + acc[rt][1][rq * 4 + 0];
        rp.y = acc[rt][0][rq * 4 + 1] + acc[rt][1][rq * 4 + 1];
        rp.z = acc[rt][0][rq * 4 + 2] + acc[rt][1][rq * 4 + 2];
        rp.w = acc[rt][0][rq * 4 + 3] + acc[rt][1][rq * 4 + 3];
        *(float4*)&rowbuf[(wr * 64 + wc * 32 + m) * 76 + rt * 32 + rq * 8 + h * 4] = rp;
      }
    asm volatile("s_waitcnt lgkmcnt(0)" ::: "memory");
    __builtin_amdgcn_s_barrier();
    asm volatile("" ::: "memory");

    // phase2 rows: own-half slots normalized by wave (wr, wc_w=h)'s msub, partner's
    // half by wave (wr, h^1)'s msub — merge each under its own max (zero-skip).
    {
      float s = 0.f;
      #pragma unroll
      for (int k = 0; k < 32; ++k)
        s += rowbuf[(wr * 64 + h * 32 + k) * 76 + wc * 32 + m];
      float mh = wmaxb[wr * 2 + h];
      float mo = wmaxb[wr * 2 + (h ^ 1)];
      float so = __shfl_xor(s, 32);
      if (s > 0.f) {
        if (mh > Mr) { Sr = Sr * HEXP2(Mr - mh) + s; Mr = mh; }
        else         { Sr += s * HEXP2(mh - Mr); }
      }
      if (so > 0.f) {
        if (mo > Mr) { Sr = Sr * HEXP2(Mr - mo) + so; Mr = mo; }
        else         { Sr += so * HEXP2(mo - Mr); }
      }
    }
    // phase2 cols: merge wr=0/1 partials (each carries its own msub) -> pC
    if (tid < 128) {
      float2 c0 = colbuf[tid], c1 = colbuf[128 + tid];
      float M = -3.0e38f, L = 0.f;
      if (c0.y > 0.f) { M = c0.x; L = c0.y; }
      if (c1.y > 0.f) {
        if (c1.x > M) { L = L * HEXP2(M - c1.x) + c1.y; M = c1.x; }
        else          { L += c1.y * HEXP2(c1.x - M); }
      }
      pC[(size_t)stripe * N_ + by * 2048 + jj * 128 + tid] = make_float2(M, L);
    }
    asm volatile("s_waitcnt lgkmcnt(0)" ::: "memory");
    __builtin_amdgcn_s_barrier();
    asm volatile("" ::: "memory");
  }

  if (h == 0)
    pR[(size_t)by * N_ + stripe * 128 + wr * 64 + wc * 32 + m] = make_float2(Mr, Sr);
}

// ---------------- merge: rows (8 partials) + cols (128 partials) -> LSE -> loss ----------------
__global__ void merge_kernel(const float2* __restrict__ pR, const float2* __restrict__ pC,
                             const float* __restrict__ diag2, float* __restrict__ accv) {
  int idx = blockIdx.x * 256 + threadIdx.x;  // 0..2N-1
  float M = -3.0e38f, L = 0.f;
  int i;
  if (idx < N_) {
    i = idx;
    #pragma unroll
    for (int g = 0; g < 8; ++g) {
      float2 w = pR[(size_t)g * N_ + i];
      if (w.y > 0.f) {
        if (w.x > M) { L = L * exp2f(M - w.x) + w.y; M = w.x; }
        else         { L += w.y * exp2f(w.x - M); }
      }
    }
  } else {
    i = idx - N_;
    for (int s = 0; s < 128; ++s) {
      float2 w = pC[(size_t)s * N_ + i];
      if (w.y > 0.f) {
        if (w.x > M) { L = L * exp2f(M - w.x) + w.y; M = w.x; }
        else         { L += w.y * exp2f(w.x - M); }
      }
    }
  }
  float val = (M + log2f(fmaxf(L, 1e-45f))) - diag2[i];
  val = fminf(fmaxf(val, -1.0e6f), 1.0e6f);  // inf-firewall (true vals are ~1e3)

  __shared__ float red[256];
  red[threadIdx.x] = val;
  __syncthreads();
  #pragma unroll
  for (int s = 128; s > 0; s >>= 1) {
    if (threadIdx.x < s) red[threadIdx.x] += red[threadIdx.x + s];
    __syncthreads();
  }
  if (threadIdx.x == 0) atomicAdd(accv, red[0]);
}

__global__ void finalize_kernel(const float* __restrict__ accv, float* __restrict__ out) {
  out[0] = accv[0] * (0.69314718055994531f / 32768.0f);  // ln2 / (2N)
}

// ---------------- launch ----------------
extern "C" void kernel_launch(void* const* d_in, const int* in_sizes, int n_in,
                              void* d_out, int out_size, void* d_ws, size_t ws_size,
                              hipStream_t stream) {
  const float* img = (const float*)d_in[0];
  const float* txt = (const float*)d_in[1];
  const float* ls  = (const float*)d_in[2];
  float* out = (float*)d_out;

  char* ws = (char*)d_ws;
  short* PA    = (short*)(ws);                 //  8 MB
  short* PB    = (short*)(ws + 8388608);       //  8 MB
  float* diag2 = (float*)(ws + 16777216);      //  64 KB
  float* accv  = (float*)(ws + 16842752);      //  256 B
  float2* pR   = (float2*)(ws + 16843008);     //  1 MB  (8 x N)
  float2* pC   = (float2*)(ws + 17891584);     //  16 MB (128 x N)

  hipLaunchKernelGGL(prep_pack, dim3(2048), dim3(256), 0, stream, img, txt, ls, PA, PB, accv);
  hipLaunchKernelGGL(diag_kernel, dim3(N_ / 4), dim3(256), 0, stream, img, txt, ls, diag2);
  hipLaunchKernelGGL(gemm_stats, dim3(128, 8), dim3(256), 0, stream, PA, PB, pR, pC);
  hipLaunchKernelGGL(merge_kernel, dim3(2 * N_ / 256), dim3(256), 0, stream, pR, pC, diag2, accv);
  hipLaunchKernelGGL(finalize_kernel, dim3(1), dim3(1), 0, stream, accv, out);
}